// Round 5
// baseline (200.436 us; speedup 1.0000x reference)
//
#include <hip/hip_runtime.h>
#include <math.h>

#define Bn 8
#define Hn 256
#define Wn 256
#define HW (Hn * Wn)

// Load a 3x6 window (rows h-1..h+1, cols w0-1..w0+4), zero-padded borders.
// w0 is a multiple of 4 so the middle 4 cols are one aligned float4.
__device__ __forceinline__ void load_win6(const float* __restrict__ plane,
                                          int h, int w0, float win[3][6]) {
#pragma unroll
  for (int r = 0; r < 3; ++r) {
    int hh = h - 1 + r;
    bool okh = (unsigned)hh < (unsigned)Hn;
    const float* row = plane + hh * Wn;
    if (okh) {
      float4 mid = *(const float4*)(row + w0);
      win[r][0] = (w0 > 0) ? row[w0 - 1] : 0.f;
      win[r][1] = mid.x; win[r][2] = mid.y; win[r][3] = mid.z; win[r][4] = mid.w;
      win[r][5] = (w0 + 4 < Wn) ? row[w0 + 4] : 0.f;
    } else {
#pragma unroll
      for (int c = 0; c < 6; ++c) win[r][c] = 0.f;
    }
  }
}

// Kernel A: fused per-neighbor conv1(2->64,3x3)+ReLU -> conv2(64->1,1x1)
// -> sigmoid -> gate neighbor. Writes "combined" (B,7,H,W) into ws.
//
// R5: NO LDS. Weights are wave-uniform -> read with uniform indices so the
// compiler emits s_load into SGPRs (scalar pipe issues in parallel with
// VALU; fmaf takes the SGPR operand directly). This removes the weight
// delivery cost that bound R2 (LDS pipe 1.5x oversubscribed) and R4 (the
// allocator squeezed the 8-px structure to 64 VGPRs and shuffled windows
// through AGPRs). 4 px/thread (~60 VGPR natural, no allocator fight),
// grid 6 x 512 = 3072 blocks = 12 blocks/CU.
//
// Channel swap for n>=3 handled by swapping PLANE pointers (uniform), not
// weights: pair = [base,check] for n<3, [check,base] for n>=3. win0 always
// multiplies weight ch0 (W1[..][0]), win1 ch1.
__global__ __launch_bounds__(256, 4) void sim_kernel(
    const float* __restrict__ x,   // (8,7,256,256)
    const float* __restrict__ W1,  // (6,64,2,3,3)
    const float* __restrict__ b1,  // (6,64)
    const float* __restrict__ W2,  // (6,1,64,1,1)
    const float* __restrict__ b2,  // (6,1)
    float* __restrict__ comb)      // (8,7,256,256)
{
  int n  = blockIdx.x / 512;    // neighbor 0..5 (uniform)
  int pb = blockIdx.x & 511;    // pixel block 0..511

  int idx = pb * 256 + threadIdx.x;  // over B*H*W/4 = 131072
  int w0 = (idx & 63) << 2;
  int h  = (idx >> 6) & (Hn - 1);
  int b  = idx >> 14;

  const float* xb = x + (size_t)b * 7 * HW;
  float* cb = comb + (size_t)b * 7 * HW;

  int cc  = (n < 3) ? n : n + 1;   // neighbor's channel in x/comb
  int pl0 = (n < 3) ? 3 : cc;      // plane feeding conv input ch0
  int pl1 = (n < 3) ? cc : 3;      // plane feeding conv input ch1

  float win0[3][6], win1[3][6];
  load_win6(xb + (size_t)pl0 * HW, h, w0, win0);
  load_win6(xb + (size_t)pl1 * HW, h, w0, win1);

  // combined channel 3 = base (center taps) — written once, by n==0 blocks.
  // For n==0 (<3), base is win0.
  if (n == 0) {
    *(float4*)(cb + 3 * HW + h * Wn + w0) =
        make_float4(win0[1][1], win0[1][2], win0[1][3], win0[1][4]);
  }

  const float* wbase = W1 + (size_t)n * 64 * 18;  // uniform
  const float* b1n   = b1 + n * 64;
  const float* w2n   = W2 + n * 64;

  float s0 = 0.f, s1 = 0.f, s2 = 0.f, s3 = 0.f;
#pragma unroll 2
  for (int c = 0; c < 64; ++c) {
    const float* w = wbase + c * 18;   // uniform -> s_load
    float bias = b1n[c];               // uniform -> s_load
    float w2v  = w2n[c];               // uniform -> s_load
    float a0 = bias, a1 = bias, a2 = bias, a3 = bias;
#pragma unroll
    for (int dy = 0; dy < 3; ++dy) {
#pragma unroll
      for (int dx = 0; dx < 3; ++dx) {
        float wv0 = w[dy * 3 + dx];
        float wv1 = w[9 + dy * 3 + dx];
        a0 = fmaf(wv0, win0[dy][0 + dx], a0);
        a1 = fmaf(wv0, win0[dy][1 + dx], a1);
        a2 = fmaf(wv0, win0[dy][2 + dx], a2);
        a3 = fmaf(wv0, win0[dy][3 + dx], a3);
        a0 = fmaf(wv1, win1[dy][0 + dx], a0);
        a1 = fmaf(wv1, win1[dy][1 + dx], a1);
        a2 = fmaf(wv1, win1[dy][2 + dx], a2);
        a3 = fmaf(wv1, win1[dy][3 + dx], a3);
      }
    }
    s0 = fmaf(w2v, fmaxf(a0, 0.f), s0);
    s1 = fmaf(w2v, fmaxf(a1, 0.f), s1);
    s2 = fmaf(w2v, fmaxf(a2, 0.f), s2);
    s3 = fmaf(w2v, fmaxf(a3, 0.f), s3);
  }

  float bb = b2[n];
  float g0 = 1.f / (1.f + expf(-(s0 + bb)));
  float g1 = 1.f / (1.f + expf(-(s1 + bb)));
  float g2 = 1.f / (1.f + expf(-(s2 + bb)));
  float g3 = 1.f / (1.f + expf(-(s3 + bb)));

  // Gate the CHECK plane's center taps: check window is win1 for n<3, win0
  // for n>=3 (uniform select).
  float c0 = (n < 3) ? win1[1][1] : win0[1][1];
  float c1 = (n < 3) ? win1[1][2] : win0[1][2];
  float c2 = (n < 3) ? win1[1][3] : win0[1][3];
  float c3 = (n < 3) ? win1[1][4] : win0[1][4];
  *(float4*)(cb + (size_t)cc * HW + h * Wn + w0) =
      make_float4(g0 * c0, g1 * c1, g2 * c2, g3 * c3);
}

// Kernel B: final mixing conv (7->7, 3x3, SAME). 2 px/thread -> 1024 blocks
// (4 blocks/CU). R5: ic loop ROLLED (R4's full unroll wanted 448 weights
// SGPR-resident -> impossible -> degenerate weight path); per ic-iter only
// 63 uniform weight floats are live -> clean s_load pipelining. oc + taps
// fully unrolled; acc[7][2] + win[3][4] stay in VGPRs (~50).
__global__ __launch_bounds__(256) void mix_kernel(
    const float* __restrict__ comb,  // (8,7,256,256)
    const float* __restrict__ Wm,    // (7,7,3,3)
    const float* __restrict__ bm,    // (7,)
    float* __restrict__ out)         // (8,7,256,256)
{
  int idx = blockIdx.x * 256 + threadIdx.x;  // over B*H*W/2 = 262144
  int w0 = (idx & 127) << 1;
  int h  = (idx >> 7) & (Hn - 1);
  int b  = idx >> 15;
  const float* cbase = comb + (size_t)b * 7 * HW;

  float acc[7][2];
#pragma unroll
  for (int oc = 0; oc < 7; ++oc) {
    float bv = bm[oc];  // uniform -> s_load
    acc[oc][0] = bv;
    acc[oc][1] = bv;
  }

#pragma unroll 1
  for (int ic = 0; ic < 7; ++ic) {
    // 3x4 window: rows h-1..h+1, cols w0-1..w0+2
    float win[3][4];
    const float* plane = cbase + (size_t)ic * HW;
#pragma unroll
    for (int r = 0; r < 3; ++r) {
      int hh = h - 1 + r;
      bool okh = (unsigned)hh < (unsigned)Hn;
      const float* row = plane + hh * Wn;
      if (okh) {
        float2 mid = *(const float2*)(row + w0);
        win[r][0] = (w0 > 0) ? row[w0 - 1] : 0.f;
        win[r][1] = mid.x;
        win[r][2] = mid.y;
        win[r][3] = (w0 + 2 < Wn) ? row[w0 + 2] : 0.f;
      } else {
        win[r][0] = win[r][1] = win[r][2] = win[r][3] = 0.f;
      }
    }
#pragma unroll
    for (int oc = 0; oc < 7; ++oc) {
      const float* wp = Wm + (oc * 7 + ic) * 9;  // uniform -> s_load
#pragma unroll
      for (int dy = 0; dy < 3; ++dy) {
#pragma unroll
        for (int dx = 0; dx < 3; ++dx) {
          float wvv = wp[dy * 3 + dx];
          acc[oc][0] = fmaf(wvv, win[dy][0 + dx], acc[oc][0]);
          acc[oc][1] = fmaf(wvv, win[dy][1 + dx], acc[oc][1]);
        }
      }
    }
  }

  float* ob = out + (size_t)b * 7 * HW + h * Wn + w0;
#pragma unroll
  for (int oc = 0; oc < 7; ++oc)
    *(float2*)(ob + (size_t)oc * HW) = make_float2(acc[oc][0], acc[oc][1]);
}

extern "C" void kernel_launch(void* const* d_in, const int* in_sizes, int n_in,
                              void* d_out, int out_size, void* d_ws, size_t ws_size,
                              hipStream_t stream) {
  const float* x  = (const float*)d_in[0];
  const float* W1 = (const float*)d_in[1];
  const float* b1 = (const float*)d_in[2];
  const float* W2 = (const float*)d_in[3];
  const float* b2 = (const float*)d_in[4];
  const float* Wm = (const float*)d_in[5];
  const float* bm = (const float*)d_in[6];
  float* out  = (float*)d_out;
  float* comb = (float*)d_ws;  // 8*7*256*256 floats = 14.7 MB

  sim_kernel<<<6 * 512, 256, 0, stream>>>(x, W1, b1, W2, b2, comb);
  mix_kernel<<<1024, 256, 0, stream>>>(comb, Wm, bm, out);
}

// Round 6
// 139.403 us; speedup vs baseline: 1.4378x; 1.4378x over previous
//
#include <hip/hip_runtime.h>
#include <math.h>

#define Bn 8
#define Hn 256
#define Wn 256
#define HW (Hn * Wn)

typedef __attribute__((ext_vector_type(8))) short bf16x8;
typedef __attribute__((ext_vector_type(4))) float f32x4;

// fp32 -> bf16 (round-to-nearest-even), returns raw bits
__device__ __forceinline__ unsigned int f2bf(float f) {
  unsigned int u = __float_as_uint(f);
  unsigned int r = u + 0x7FFFu + ((u >> 16) & 1u);
  return r >> 16;
}

// Kernel A (R6, MFMA): fused per-neighbor conv1(2->64,3x3)+ReLU ->
// conv2(64->1,1x1) -> sigmoid -> gate. conv1 runs on matrix cores in bf16
// (K=18 padded to 32); conv2/sigmoid/gating stay fp32 on VALU, so bf16 error
// enters only through the sigmoid argument (slope <= 0.25).
//
// One block = one (neighbor n, batch b, row h) = 256 pixels.
//   - im2col tile in LDS: [256 px][32 k] bf16, 80 B stride (16B-aligned
//     b128 ops, 2-way-free bank pattern). k = [base taps 0..8 | check taps
//     0..8 | 14 zeros]. One thread per pixel: 18 coalesced predicated loads.
//   - W1 repacked per block into MFMA A-layout in LDS (bf16), with the
//     n>=3 base/check weight-channel swap folded in.
//   - Each wave: 4 strips of 16 px; per strip 1 ds_read_b128 B-frag +
//     4x mfma_f32_16x16x32_bf16 (ch groups) + fp32 epilogue:
//     s = sum_ch w2*relu(acc) (16 FMA) -> shfl_xor(16,32) quad reduce ->
//     sigmoid -> gate with fp32 check-center from LDS.
__global__ __launch_bounds__(256) void sim_kernel(
    const float* __restrict__ x,   // (8,7,256,256)
    const float* __restrict__ W1,  // (6,64,2,3,3)
    const float* __restrict__ b1,  // (6,64)
    const float* __restrict__ W2,  // (6,1,64,1,1)
    const float* __restrict__ b2,  // (6,1)
    float* __restrict__ comb)      // (8,7,256,256)
{
  __shared__ unsigned int imcol[256 * 20];  // 20 KB: [px][20 uints], 16 used
  __shared__ unsigned int wlds[1024];       // 4 KB: A frags [f][q][m][4]
  __shared__ float ccfp[256];               // fp32 check-center per px

  int bi = blockIdx.x;
  int n = bi >> 11;          // 0..5
  int b = (bi >> 8) & 7;     // 0..7
  int h = bi & 255;          // 0..255
  int cc = (n < 3) ? n : n + 1;
  int t = threadIdx.x;

  const float* xb     = x + (size_t)b * 7 * HW;
  const float* basep  = xb + 3 * HW;
  const float* checkp = xb + (size_t)cc * HW;

  // ---- stage A (weights) in MFMA layout: t = f*64 + q*16 + m ----
  {
    int f = t >> 6, q = (t >> 4) & 3, m = t & 15;
    int ch = 16 * f + m;
    int bsrc = (n < 3) ? 0 : 1;  // weight input-ch that multiplies BASE
    const float* wch = W1 + ((size_t)(n * 64 + ch)) * 18;  // [src][tap0..8]
    unsigned int kv[4];
#pragma unroll
    for (int jj = 0; jj < 4; ++jj) {
      int k0 = q * 8 + jj * 2;
      int k1 = k0 + 1;
      float v0 = 0.f, v1 = 0.f;
      if (k0 < 18) {
        int src = (k0 < 9) ? bsrc : 1 - bsrc;
        v0 = wch[src * 9 + (k0 < 9 ? k0 : k0 - 9)];
      }
      if (k1 < 18) {
        int src = (k1 < 9) ? bsrc : 1 - bsrc;
        v1 = wch[src * 9 + (k1 < 9 ? k1 : k1 - 9)];
      }
      kv[jj] = f2bf(v0) | (f2bf(v1) << 16);
    }
    *(uint4*)&wlds[t * 4] = make_uint4(kv[0], kv[1], kv[2], kv[3]);
  }

  // ---- stage B (im2col) for pixel px = t ----
  {
    float v[18];
#pragma unroll
    for (int pl = 0; pl < 2; ++pl) {
      const float* plane = pl ? checkp : basep;
#pragma unroll
      for (int r = 0; r < 3; ++r) {
        int hh = h - 1 + r;
        bool okh = (unsigned)hh < (unsigned)Hn;
        const float* row = plane + hh * Wn;
#pragma unroll
        for (int dx = 0; dx < 3; ++dx) {
          int c = t - 1 + dx;
          bool ok = okh && ((unsigned)c < (unsigned)Wn);
          v[pl * 9 + r * 3 + dx] = ok ? row[c] : 0.f;
        }
      }
    }
    ccfp[t] = v[9 + 4];  // check center (fp32, for gating)
    if (n == 0) {        // combined channel 3 = base plane (center)
      comb[((size_t)b * 7 + 3) * HW + h * Wn + t] = v[4];
    }
    unsigned int kv[16];
#pragma unroll
    for (int j = 0; j < 9; ++j)
      kv[j] = f2bf(v[2 * j]) | (j == 8 ? (f2bf(v[17]) << 16)
                                       : (f2bf(v[2 * j + 1]) << 16));
#pragma unroll
    for (int j = 9; j < 16; ++j) kv[j] = 0;
    uint4* dst = (uint4*)&imcol[t * 20];
    dst[0] = make_uint4(kv[0], kv[1], kv[2], kv[3]);
    dst[1] = make_uint4(kv[4], kv[5], kv[6], kv[7]);
    dst[2] = make_uint4(kv[8], kv[9], kv[10], kv[11]);
    dst[3] = make_uint4(kv[12], kv[13], kv[14], kv[15]);
  }
  __syncthreads();

  int lane = t & 63, wv = t >> 6;
  int q = lane >> 4, m_ = lane & 15;

  // A fragments (4 ch-groups), per-lane w2 / b1 (ch = 16f + 4q + r)
  bf16x8 afrag[4];
  float w2v[4][4], b1v[4][4];
#pragma unroll
  for (int f = 0; f < 4; ++f) {
    afrag[f] = *(const bf16x8*)&wlds[(f * 64 + q * 16 + m_) * 4];
    float4 tw = *(const float4*)&W2[n * 64 + 16 * f + 4 * q];
    float4 tb = *(const float4*)&b1[n * 64 + 16 * f + 4 * q];
    w2v[f][0] = tw.x; w2v[f][1] = tw.y; w2v[f][2] = tw.z; w2v[f][3] = tw.w;
    b1v[f][0] = tb.x; b1v[f][1] = tb.y; b1v[f][2] = tb.z; b1v[f][3] = tb.w;
  }
  float bb = b2[n];
  float* combcc = comb + ((size_t)b * 7 + cc) * HW + h * Wn;

#pragma unroll
  for (int i = 0; i < 4; ++i) {
    int s = wv * 4 + i;        // strip 0..15
    int px = s * 16 + m_;      // this lane's pixel column

    f32x4 acc[4];
#pragma unroll
    for (int f = 0; f < 4; ++f) {
      acc[f][0] = b1v[f][0]; acc[f][1] = b1v[f][1];
      acc[f][2] = b1v[f][2]; acc[f][3] = b1v[f][3];
    }

    bf16x8 bfrag = *(const bf16x8*)&imcol[px * 20 + q * 4];
#pragma unroll
    for (int f = 0; f < 4; ++f)
      acc[f] = __builtin_amdgcn_mfma_f32_16x16x32_bf16(afrag[f], bfrag,
                                                       acc[f], 0, 0, 0);

    // conv2 (1x1): per-lane partial over its 16 channels, then quad-reduce
    float sp = 0.f;
#pragma unroll
    for (int f = 0; f < 4; ++f)
#pragma unroll
      for (int r = 0; r < 4; ++r)
        sp = fmaf(w2v[f][r], fmaxf(acc[f][r], 0.f), sp);
    sp += __shfl_xor(sp, 16, 64);
    sp += __shfl_xor(sp, 32, 64);
    sp += bb;

    float e = __builtin_amdgcn_exp2f(sp * -1.442695041f);
    float g = __builtin_amdgcn_rcpf(1.f + e);
    float gated = g * ccfp[px];
    if (lane < 16) combcc[px] = gated;
  }
}

// Kernel B: final mixing conv (7->7, 3x3, SAME). 2 px/thread, 1024 blocks.
// (R5 version — the total-minus-sim gap is ~constant across all mix
// variants, consistent with fixed harness overhead, so leave it alone.)
__global__ __launch_bounds__(256) void mix_kernel(
    const float* __restrict__ comb,  // (8,7,256,256)
    const float* __restrict__ Wm,    // (7,7,3,3)
    const float* __restrict__ bm,    // (7,)
    float* __restrict__ out)         // (8,7,256,256)
{
  int idx = blockIdx.x * 256 + threadIdx.x;  // over B*H*W/2 = 262144
  int w0 = (idx & 127) << 1;
  int h  = (idx >> 7) & (Hn - 1);
  int b  = idx >> 15;
  const float* cbase = comb + (size_t)b * 7 * HW;

  float acc[7][2];
#pragma unroll
  for (int oc = 0; oc < 7; ++oc) {
    float bv = bm[oc];
    acc[oc][0] = bv;
    acc[oc][1] = bv;
  }

#pragma unroll 1
  for (int ic = 0; ic < 7; ++ic) {
    float win[3][4];
    const float* plane = cbase + (size_t)ic * HW;
#pragma unroll
    for (int r = 0; r < 3; ++r) {
      int hh = h - 1 + r;
      bool okh = (unsigned)hh < (unsigned)Hn;
      const float* row = plane + hh * Wn;
      if (okh) {
        float2 mid = *(const float2*)(row + w0);
        win[r][0] = (w0 > 0) ? row[w0 - 1] : 0.f;
        win[r][1] = mid.x;
        win[r][2] = mid.y;
        win[r][3] = (w0 + 2 < Wn) ? row[w0 + 2] : 0.f;
      } else {
        win[r][0] = win[r][1] = win[r][2] = win[r][3] = 0.f;
      }
    }
#pragma unroll
    for (int oc = 0; oc < 7; ++oc) {
      const float* wp = Wm + (oc * 7 + ic) * 9;
#pragma unroll
      for (int dy = 0; dy < 3; ++dy) {
#pragma unroll
        for (int dx = 0; dx < 3; ++dx) {
          float wvv = wp[dy * 3 + dx];
          acc[oc][0] = fmaf(wvv, win[dy][0 + dx], acc[oc][0]);
          acc[oc][1] = fmaf(wvv, win[dy][1 + dx], acc[oc][1]);
        }
      }
    }
  }

  float* ob = out + (size_t)b * 7 * HW + h * Wn + w0;
#pragma unroll
  for (int oc = 0; oc < 7; ++oc)
    *(float2*)(ob + (size_t)oc * HW) = make_float2(acc[oc][0], acc[oc][1]);
}

extern "C" void kernel_launch(void* const* d_in, const int* in_sizes, int n_in,
                              void* d_out, int out_size, void* d_ws, size_t ws_size,
                              hipStream_t stream) {
  const float* x  = (const float*)d_in[0];
  const float* W1 = (const float*)d_in[1];
  const float* b1 = (const float*)d_in[2];
  const float* W2 = (const float*)d_in[3];
  const float* b2 = (const float*)d_in[4];
  const float* Wm = (const float*)d_in[5];
  const float* bm = (const float*)d_in[6];
  float* out  = (float*)d_out;
  float* comb = (float*)d_ws;  // 8*7*256*256 floats = 14.7 MB

  sim_kernel<<<6 * 8 * 256, 256, 0, stream>>>(x, W1, b1, W2, b2, comb);
  mix_kernel<<<1024, 256, 0, stream>>>(comb, Wm, bm, out);
}